// Round 17
// baseline (296.507 us; speedup 1.0000x reference)
//
#include <hip/hip_runtime.h>

#define S_LEN 2048
#define HID   2048
#define NHEAD 16
#define HD    128
#define BSZ   2
#define BS_TOT (BSZ * S_LEN)   // 4096
#define QKS   4096             // row stride of fused QK buffer

typedef __bf16 bf16x8 __attribute__((ext_vector_type(8)));
typedef unsigned short u16x8 __attribute__((ext_vector_type(8)));
typedef unsigned short u16x4 __attribute__((ext_vector_type(4)));
typedef float f32x4 __attribute__((ext_vector_type(4)));

static __device__ __forceinline__ bf16x8 as_bf(u16x8 v) { return __builtin_bit_cast(bf16x8, v); }

static __device__ __forceinline__ unsigned short f2bf(float f) {
  __bf16 h = (__bf16)f;
  return __builtin_bit_cast(unsigned short, h);
}
static __device__ __forceinline__ float bf2f(unsigned short b) {
  unsigned int u = ((unsigned int)b) << 16;
  return __builtin_bit_cast(float, u);
}

// async global->LDS 16B per lane; LDS dst = wave-uniform base + lane*16
static __device__ __forceinline__ void gload_lds16(const unsigned short* g, unsigned short* l) {
  __builtin_amdgcn_global_load_lds((const __attribute__((address_space(1))) unsigned int*)g,
                                   (__attribute__((address_space(3))) unsigned int*)l, 16, 0, 0);
}

// ---------------- fused converts + rope table (one launch) ----------------
__global__ __launch_bounds__(256) void cvt_all(const float* __restrict__ hs,
                                               const float* __restrict__ Wq,
                                               const float* __restrict__ Wk,
                                               const float* __restrict__ Wv,
                                               const float* __restrict__ Wo,
                                               unsigned short* __restrict__ hsb,
                                               unsigned short* __restrict__ wall,
                                               float* __restrict__ ct, float* __restrict__ st) {
  int b = (int)blockIdx.x, tid = (int)threadIdx.x;
  if (b < 8192) {                       // hidden states: 8.39M floats
    int i = b * 256 + tid;
    float4 v = ((const float4*)hs)[i];
    ushort4 o; o.x = f2bf(v.x); o.y = f2bf(v.y); o.z = f2bf(v.z); o.w = f2bf(v.w);
    ((ushort4*)hsb)[i] = o;
  } else if (b < 24576) {               // 4 weights, 4096 blocks each
    int t = b - 8192;
    int wsel = t >> 12;
    const float* in = (wsel == 0) ? Wq : (wsel == 1) ? Wk : (wsel == 2) ? Wv : Wo;
    int i = (t & 4095) * 256 + tid;
    float4 v = ((const float4*)in)[i];
    ushort4 o; o.x = f2bf(v.x); o.y = f2bf(v.y); o.z = f2bf(v.z); o.w = f2bf(v.w);
    ((ushort4*)(wall + (size_t)wsel * HID * HID))[i] = o;
  } else {                              // rope table: 512 blocks -> [2048][64]
    int id = (b - 24576) * 256 + tid;
    int tt = id >> 6, d = id & 63;
    float inv = powf(10000.0f, -(float)d * (1.0f / 64.0f));
    float f = (float)tt * inv;
    float sv, cv;
    sincosf(f, &sv, &cv);
    ct[id] = cv; st[id] = sv;
  }
}

// ---------------- RoPE apply in-place on K half of fused QK buffer ----------------
__global__ __launch_bounds__(256) void rope_apply_k(unsigned short* __restrict__ qk,
                                                    const float* __restrict__ ct,
                                                    const float* __restrict__ st) {
  int id = blockIdx.x * 256 + threadIdx.x;   // BS_TOT*NHEAD*16 threads; each does 4 d's
  int d4 = (id & 15) * 4;
  int h = (id >> 4) & (NHEAD - 1);
  int m = id >> 8;
  int s = m & (S_LEN - 1);
  float4 c  = *(const float4*)(ct + s * 64 + d4);
  float4 sn = *(const float4*)(st + s * 64 + d4);
  size_t base = (size_t)m * QKS + 2048 + h * HD + d4;   // K half
  u16x4 k1 = *(u16x4*)(qk + base), k2 = *(u16x4*)(qk + base + 64);
  u16x4 p1, p2;
  float cc[4] = {c.x, c.y, c.z, c.w}, ss[4] = {sn.x, sn.y, sn.z, sn.w};
#pragma unroll
  for (int j = 0; j < 4; ++j) {
    float ak = bf2f(k1[j]), bk = bf2f(k2[j]);
    p1[j] = f2bf(ak * cc[j] - bk * ss[j]);
    p2[j] = f2bf(bk * cc[j] + ak * ss[j]);
  }
  *(u16x4*)(qk + base) = p1;
  *(u16x4*)(qk + base + 64) = p2;
}

// ---------------- GEMM 256x256, BK=64, 8 waves (2Mx4N), 8-phase schedule ----------------
template <typename OutT>
__global__ __launch_bounds__(512, 1) void gemm256(const unsigned short* __restrict__ A,
                                                  const unsigned short* __restrict__ Bw,
                                                  OutT* __restrict__ C, int M, int N, int K) {
  __shared__ __align__(16) unsigned short As[2][256 * 64];
  __shared__ __align__(16) unsigned short Bs[2][256 * 64];
  int x = (int)blockIdx.x;
  int chunk = (int)gridDim.x >> 3;
  int x2 = (x & 7) * chunk + (x >> 3);   // XCD-contiguous chunks (grid % 8 == 0)
  const int nbn = N >> 8;
  int bm = x2 / nbn, bn = x2 % nbn;
  int tid = (int)threadIdx.x;
  int l = tid & 63, lr = l & 15, lg = l >> 4;
  int w = tid >> 6;                      // 0..7
  int wm = w >> 2, wn = w & 3;

  // staging sources (sigma = row&7 = l>>3 folded into per-lane global col)
  int arow0 = wm * 128 + 8 * (w & 3) + (l >> 3);   // + 32c per A-chunk
  int brow0 = 8 * w + (l >> 3);                    // + 64c per B-chunk
  int sslot = ((l & 7) ^ (l >> 3)) * 8;
  const unsigned short* gAb = A + (size_t)(bm * 256 + arow0) * K + sslot;
  const unsigned short* gBb = Bw + (size_t)(bn * 256 + brow0) * K + sslot;

  // frag read bases (row stride 64 elems; 16 rows = 1024 elems)
  int arw = (wm * 128 + lr) * 64;
  int brw = (wn * 64 + lr) * 64;
  int acol0 = ((0 + lg) ^ (lr & 7)) * 8;   // ks=0 slots 0..3
  int acol1 = ((4 + lg) ^ (lr & 7)) * 8;   // ks=1 slots 4..7

  f32x4 zero = {0.f, 0.f, 0.f, 0.f};
  f32x4 acc[8][4];
#pragma unroll
  for (int mi = 0; mi < 8; ++mi)
#pragma unroll
    for (int ni = 0; ni < 4; ++ni) acc[mi][ni] = zero;

  int nk = K >> 6;        // K-tiles of 64 (K=2048 -> 32, pow2)
  int nk2 = nk >> 1;

#define ISSUE_A(buf, tile, c)                                                  \
  gload_lds16(gAb + (size_t)(32 * (c)) * K + (tile) * 64,                      \
              &As[buf][8192 * wm + 2048 * (c) + 512 * (w & 3)])
#define ISSUE_B(buf, tile, c)                                                  \
  gload_lds16(gBb + (size_t)(64 * (c)) * K + (tile) * 64,                      \
              &Bs[buf][4096 * (c) + 512 * w])
#define HT(buf, tile, c)                                                       \
  do { ISSUE_B(buf, tile, c); ISSUE_A(buf, tile, c); } while (0)
#define VM6 asm volatile("s_waitcnt vmcnt(6)" ::: "memory")

#define LOADB(d)                                                               \
  do {                                                                         \
    _Pragma("unroll") for (int ni = 0; ni < 4; ++ni) {                         \
      bfr[ni][0] = *(const u16x8*)&Bs[d][brw + ni * 1024 + acol0];             \
      bfr[ni][1] = *(const u16x8*)&Bs[d][brw + ni * 1024 + acol1];             \
    }                                                                          \
  } while (0)

#define PHASE(d, q, LASTW, ...)                                                \
  do {                                                                         \
    u16x8 paf[2][2];                                                           \
    _Pragma("unroll") for (int m2 = 0; m2 < 2; ++m2) {                         \
      paf[m2][0] = *(const u16x8*)&As[d][arw + ((q) * 2 + m2) * 1024 + acol0]; \
      paf[m2][1] = *(const u16x8*)&As[d][arw + ((q) * 2 + m2) * 1024 + acol1]; \
    }                                                                          \
    __VA_ARGS__;                                                               \
    __builtin_amdgcn_sched_barrier(0);                                         \
    __builtin_amdgcn_s_barrier();                                              \
    __builtin_amdgcn_s_setprio(1);                                             \
    _Pragma("unroll") for (int m2 = 0; m2 < 2; ++m2)                           \
      _Pragma("unroll") for (int ni = 0; ni < 4; ++ni) {                       \
        acc[(q) * 2 + m2][ni] = __builtin_amdgcn_mfma_f32_16x16x32_bf16(       \
            as_bf(paf[m2][0]), as_bf(bfr[ni][0]), acc[(q) * 2 + m2][ni], 0, 0, 0); \
        acc[(q) * 2 + m2][ni] = __builtin_amdgcn_mfma_f32_16x16x32_bf16(       \
            as_bf(paf[m2][1]), as_bf(bfr[ni][1]), acc[(q) * 2 + m2][ni], 0, 0, 0); \
      }                                                                        \
    __builtin_amdgcn_s_setprio(0);                                             \
    LASTW;                                                                     \
    __builtin_amdgcn_s_barrier();                                              \
  } while (0)

  // prologue: tile0 4 half-tiles + tile1 3 half-tiles (14 loads), land tile0, sync
  HT(0, 0, 0); HT(0, 0, 1); HT(0, 0, 2); HT(0, 0, 3);
  HT(1, 1, 0); HT(1, 1, 1); HT(1, 1, 2);
  VM6;
  __builtin_amdgcn_s_barrier();

  for (int t = 0; t < nk2; ++t) {
    int Todd = 2 * t + 1;                 // always < nk
    int T2 = (2 * t + 2) & (nk - 1);      // wrap-around dummies at tail
    int T3 = (2 * t + 3) & (nk - 1);
    u16x8 bfr[4][2];
    LOADB(0);
    PHASE(0, 0, (void)0, HT(1, Todd, 3));
    PHASE(0, 1, (void)0, HT(0, T2, 0));
    PHASE(0, 2, (void)0, HT(0, T2, 1));
    PHASE(0, 3, VM6,     HT(0, T2, 2));
    LOADB(1);
    PHASE(1, 0, (void)0, HT(0, T2, 3));
    PHASE(1, 1, (void)0, HT(1, T3, 0));
    PHASE(1, 2, (void)0, HT(1, T3, 1));
    PHASE(1, 3, VM6,     HT(1, T3, 2));
  }
#undef PHASE
#undef LOADB
#undef VM6
#undef HT
#undef ISSUE_A
#undef ISSUE_B

#pragma unroll
  for (int mi = 0; mi < 8; ++mi) {
#pragma unroll
    for (int ni = 0; ni < 4; ++ni) {
      int col = bn * 256 + wn * 64 + ni * 16 + lr;
#pragma unroll
      for (int j = 0; j < 4; ++j) {
        int rowm = bm * 256 + wm * 128 + mi * 16 + 4 * lg + j;
        float v = acc[mi][ni][j];
        if constexpr (sizeof(OutT) == 2) C[(size_t)rowm * N + col] = f2bf(v);
        else                             C[(size_t)rowm * N + col] = v;
      }
    }
  }
  (void)M;
}

// ---------------- GEMM 128x128, BK=32, 4 waves; 4-buffer counted-vmcnt ----------------
template <typename OutT>
__global__ __launch_bounds__(256) void gemm128(const unsigned short* __restrict__ A,
                                               const unsigned short* __restrict__ Bw,
                                               OutT* __restrict__ C, int M, int N, int K) {
  __shared__ __align__(16) unsigned short As[4][128 * 32];
  __shared__ __align__(16) unsigned short Bs[4][128 * 32];
  int x = (int)blockIdx.x;
  int chunk = (int)gridDim.x >> 3;
  int x2 = (x & 7) * chunk + (x >> 3);
  const int nbn = N >> 7;
  int bm = x2 / nbn, bn = x2 % nbn;
  int tid = (int)threadIdx.x;
  int l = tid & 63, lr = l & 15, lg = l >> 4;
  int w = tid >> 6, wm = w >> 1, wn = w & 1;

  int w32 = 32 * w;
  int srow = w32 + (l >> 2);
  int ssw = ((l >> 2) ^ (l >> 4)) & 3;
  const unsigned short* gA = A + (size_t)(bm * 128 + srow) * K + (((l & 3) ^ ssw) << 3);
  const unsigned short* gB = Bw + (size_t)(bn * 128 + srow) * K + (((l & 3) ^ ssw) << 3);

  int rsw = (lr ^ (lr >> 2)) & 3;
  int aoff[4], boff[4];
#pragma unroll
  for (int i = 0; i < 4; ++i) {
    aoff[i] = (wm * 64 + i * 16 + lr) * 32 + ((lg ^ rsw) << 3);
    boff[i] = (wn * 64 + i * 16 + lr) * 32 + ((lg ^ rsw) << 3);
  }

  f32x4 zero = {0.f, 0.f, 0.f, 0.f};
  f32x4 acc[4][4];
#pragma unroll
  for (int mi = 0; mi < 4; ++mi)
#pragma unroll
    for (int ni = 0; ni < 4; ++ni) acc[mi][ni] = zero;

  int nk = K >> 5;

#define STAGE(buf, kt)                                                        \
  do {                                                                        \
    const unsigned short* pa_ = gA + (size_t)(kt) * 32;                       \
    const unsigned short* pb_ = gB + (size_t)(kt) * 32;                       \
    gload_lds16(pa_, &As[buf][w32 * 32]);                                     \
    gload_lds16(pa_ + (size_t)16 * K, &As[buf][(w32 + 16) * 32]);             \
    gload_lds16(pb_, &Bs[buf][w32 * 32]);                                     \
    gload_lds16(pb_ + (size_t)16 * K, &Bs[buf][(w32 + 16) * 32]);             \
  } while (0)

#define COMPUTE(buf)                                                          \
  do {                                                                        \
    u16x8 af[4], bfr[4];                                                      \
    _Pragma("unroll") for (int i = 0; i < 4; ++i) {                           \
      af[i] = *(const u16x8*)&As[buf][aoff[i]];                               \
      bfr[i] = *(const u16x8*)&Bs[buf][boff[i]];                              \
    }                                                                         \
    _Pragma("unroll") for (int mi = 0; mi < 4; ++mi)                          \
        _Pragma("unroll") for (int ni = 0; ni < 4; ++ni)                      \
            acc[mi][ni] = __builtin_amdgcn_mfma_f32_16x16x32_bf16(            \
                as_bf(af[mi]), as_bf(bfr[ni]), acc[mi][ni], 0, 0, 0);         \
  } while (0)

  STAGE(0, 0);
  STAGE(1, 1);
  STAGE(2, 2);
  asm volatile("s_waitcnt vmcnt(8)" ::: "memory");
  __builtin_amdgcn_s_barrier();
#pragma unroll 4
  for (int kt = 0; kt < nk; ++kt) {
    COMPUTE(kt & 3);
    asm volatile("s_waitcnt vmcnt(4) lgkmcnt(0)" ::: "memory");
    __builtin_amdgcn_s_barrier();
    STAGE((kt + 3) & 3, (kt + 3) & (nk - 1));
  }
#undef STAGE
#undef COMPUTE

#pragma unroll
  for (int mi = 0; mi < 4; ++mi) {
#pragma unroll
    for (int ni = 0; ni < 4; ++ni) {
      int col = bn * 128 + wn * 64 + ni * 16 + lr;
#pragma unroll
      for (int j = 0; j < 4; ++j) {
        int rowm = bm * 128 + wm * 64 + mi * 16 + 4 * lg + j;
        float v = acc[mi][ni][j];
        if constexpr (sizeof(OutT) == 2) C[(size_t)rowm * N + col] = f2bf(v);
        else                             C[(size_t)rowm * N + col] = v;
      }
    }
  }
  (void)M;
}

// ---------------- Flash attention v9: single-buffer K/V (48KB LDS) + kv-split, UNCAPPED regs ----------------
// R15 structure minus the fatal __launch_bounds__ min-wave cap (which forced an 84-VGPR
// allocation and 831MB of scratch spill). LDS 48KB -> up to 3 blocks/CU at ~170 VGPR.
// Round: QK+V-hoist (read K/V LDS) -> s_barrier -> DMA-stage(t+1) same buffers ->
// softmax/P/PV (regs+Ps) -> __syncthreads (drains DMA).
__global__ __launch_bounds__(256) void attn_fwd(const unsigned short* __restrict__ qk,
                                                const unsigned short* __restrict__ vt,
                                                unsigned short* __restrict__ ctx,
                                                const float* __restrict__ ct,
                                                const float* __restrict__ st,
                                                unsigned short* __restrict__ pO,
                                                float* __restrict__ pls) {
  __shared__ __align__(16) unsigned short Ks[64 * 128];    // 16KB single buffer
  __shared__ __align__(16) unsigned short Vs[128 * 64];    // 16KB single buffer
  __shared__ __align__(16) unsigned short Ps[4 * 32 * 64]; // 16KB per-wave P

  int x = (int)blockIdx.x;
  int bh, qt, half, tile0, ntL;
  bool split;
  if (x < 512) {
    split = true;
    bh = x & 31;
    int pair = x >> 5;            // 0..15
    qt = 15 - (pair >> 1);        // 15..8, longest first
    half = pair & 1;
    ntL = qt + 1;                 // 16..9 rounds
    tile0 = half * ntL;
  } else {
    split = false;
    int i = x - 512;
    bh = i & 31;
    qt = 7 - (i >> 5);            // 7..0, longest first
    half = 0;
    ntL = 2 * qt + 2;             // 16..2 rounds
    tile0 = 0;
  }
  int b = bh >> 4, h = bh & 15;
  int q0 = qt * 128;

  int tid = (int)threadIdx.x;
  int w = tid >> 6, l = tid & 63, lr = l & 15, lg = l >> 4;
  const float CEXP = 0.12751744f;     // (1/sqrt(128)) * log2(e)
  const float MB   = -23.0831391f;    // -16 * log2(e): fixed-max shift
  const int bS = b * S_LEN, h128 = h * HD;
  const int qw = q0 + w * 32;
  const unsigned short* qg = qk;
  const unsigned short* kg = qk + 2048;

  // ---- Q fragments + in-register RoPE ----
  u16x8 qfr[2][4];
#pragma unroll
  for (int qf = 0; qf < 2; ++qf) {
    const unsigned short* qb = qg + (size_t)(bS + qw + qf * 16 + lr) * QKS + h128;
#pragma unroll
    for (int kk = 0; kk < 4; ++kk) qfr[qf][kk] = *(const u16x8*)(qb + kk * 32 + lg * 8);
    int spos = qw + qf * 16 + lr;     // seq position (< 2048)
#pragma unroll
    for (int kk = 0; kk < 2; ++kk) {
      int d0 = kk * 32 + lg * 8;
      float4 c0 = *(const float4*)(ct + spos * 64 + d0);
      float4 c1 = *(const float4*)(ct + spos * 64 + d0 + 4);
      float4 s0 = *(const float4*)(st + spos * 64 + d0);
      float4 s1 = *(const float4*)(st + spos * 64 + d0 + 4);
      float cc[8] = {c0.x, c0.y, c0.z, c0.w, c1.x, c1.y, c1.z, c1.w};
      float sv[8] = {s0.x, s0.y, s0.z, s0.w, s1.x, s1.y, s1.z, s1.w};
      u16x8 lo = qfr[qf][kk], hi = qfr[qf][kk + 2];
#pragma unroll
      for (int j = 0; j < 8; ++j) {
        float a = bf2f(lo[j]), b2 = bf2f(hi[j]);
        lo[j] = f2bf(a * cc[j] - b2 * sv[j]);
        hi[j] = f2bf(b2 * cc[j] + a * sv[j]);
      }
      qfr[qf][kk] = lo; qfr[qf][kk + 2] = hi;
    }
  }

  // staging sources (sigma folded into per-lane global col, rule 21)
  const unsigned short* kbg[4];
  const unsigned short* vbg[4];
#pragma unroll
  for (int i = 0; i < 4; ++i) {
    int rr = 16 * w + 4 * i + (l >> 4);           // local kv row 0..63
    int colK = ((l & 15) ^ (rr & 15)) * 8;
    kbg[i] = kg + (size_t)(bS + rr) * QKS + h128 + colK;
    int vd = 32 * w + 8 * i + (l >> 3);           // local d row 0..127
    int colV = ((l & 7) ^ (vd & 7)) * 8;
    vbg[i] = vt + (size_t)(h128 + vd) * BS_TOT + bS + colV;
  }

#define ASTAGE(t)                                                             \
  do {                                                                        \
    size_t koff_ = (size_t)(t) * 64 * QKS;                                    \
    int voff_ = (t) * 64;                                                     \
    _Pragma("unroll") for (int i_ = 0; i_ < 4; ++i_) {                        \
      gload_lds16(kbg[i_] + koff_, &Ks[(16 * w + 4 * i_) * 128]);             \
      gload_lds16(vbg[i_] + voff_, &Vs[(32 * w + 8 * i_) * 64]);              \
    }                                                                         \
  } while (0)

  f32x4 zero = {0.f, 0.f, 0.f, 0.f};
  f32x4 oacc[2][8];
#pragma unroll
  for (int qf = 0; qf < 2; ++qf)
#pragma unroll
    for (int nj = 0; nj < 8; ++nj) oacc[qf][nj] = zero;
  float lsum[2] = {0.f, 0.f};   // per-lane partials; reduced in epilogue

  ASTAGE(tile0);
  __syncthreads();              // tile0 landed

  for (int tl = 0; tl < ntL; ++tl) {
    int t = tile0 + tl;
    int k0 = t * 64;
    bool active = (k0 <= qw + 31);

    f32x4 sac[2][4];
    u16x8 vfr[2][8];
    if (active) {
      // ---- S^T = K Q^T for both qf (reads Ks) ----
#pragma unroll
      for (int qf = 0; qf < 2; ++qf)
#pragma unroll
        for (int ni = 0; ni < 4; ++ni) sac[qf][ni] = zero;
      __builtin_amdgcn_s_setprio(1);
#pragma unroll
      for (int kk = 0; kk < 4; ++kk) {
#pragma unroll
        for (int ni = 0; ni < 4; ++ni) {
          u16x8 kf = *(const u16x8*)&Ks[(ni * 16 + lr) * 128 + (((kk * 4 + lg) ^ lr) * 8)];
          sac[0][ni] = __builtin_amdgcn_mfma_f32_16x16x32_bf16(as_bf(kf), as_bf(qfr[0][kk]), sac[0][ni], 0, 0, 0);
          sac[1][ni] = __builtin_amdgcn_mfma_f32_16x16x32_bf16(as_bf(kf), as_bf(qfr[1][kk]), sac[1][ni], 0, 0, 0);
        }
      }
      __builtin_amdgcn_s_setprio(0);
      // ---- hoist V fragments to registers (reads Vs) ----
#pragma unroll
      for (int kk2 = 0; kk2 < 2; ++kk2)
#pragma unroll
        for (int nj = 0; nj < 8; ++nj)
          vfr[kk2][nj] = *(const u16x8*)&Vs[(nj * 16 + lr) * 64 + (((kk2 * 4 + lg) ^ (lr & 7)) * 8)];
    }

    __syncthreads();            // all waves done reading Ks/Vs
    if (tl + 1 < ntL) ASTAGE(t + 1);   // DMA overwrite; lands before round-end drain

    if (active) {
      bool needmask = (k0 + 63 > qw);
      unsigned short* pw = &Ps[w * 2048];
      // ---- per-qf: softmax -> P-write -> PV (PV0 MFMAs overlap softmax1 VALU) ----
#pragma unroll
      for (int qf = 0; qf < 2; ++qf) {
        float s[4][4];
#pragma unroll
        for (int ni = 0; ni < 4; ++ni)
#pragma unroll
          for (int j = 0; j < 4; ++j) s[ni][j] = sac[qf][ni][j];
        if (needmask) {
          int qgl = qw + qf * 16 + lr;
#pragma unroll
          for (int ni = 0; ni < 4; ++ni)
#pragma unroll
            for (int j = 0; j < 4; ++j)
              if (k0 + ni * 16 + 4 * lg + j > qgl) s[ni][j] = -1e30f;
        }
        float rs = 0.f;
#pragma unroll
        for (int ni = 0; ni < 4; ++ni)
#pragma unroll
          for (int j = 0; j < 4; ++j) {
            float p = exp2f(fmaf(s[ni][j], CEXP, MB));
            s[ni][j] = p; rs += p;
          }
        lsum[qf] += rs;
#pragma unroll
        for (int ni = 0; ni < 4; ++ni) {
          u16x4 pv = {f2bf(s[ni][0]), f2bf(s[ni][1]), f2bf(s[ni][2]), f2bf(s[ni][3])};
          *(u16x4*)&pw[(qf * 16 + lr) * 64 + (((2 * ni + (lg >> 1)) ^ (lr & 7)) * 8) + (lg & 1) * 4] = pv;
        }
        __builtin_amdgcn_s_setprio(1);
#pragma unroll
        for (int kk2 = 0; kk2 < 2; ++kk2) {
          u16x8 pa = *(const u16x8*)&pw[(qf * 16 + lr) * 64 + (((kk2 * 4 + lg) ^ (lr & 7)) * 8)];
#pragma unroll
          for (int nj = 0; nj < 8; ++nj)
            oacc[qf][nj] = __builtin_amdgcn_mfma_f32_16x16x32_bf16(as_bf(pa), as_bf(vfr[kk2][nj]), oacc[qf][nj], 0, 0, 0);
        }
        __builtin_amdgcn_s_setprio(0);
      }
    }

    __syncthreads();            // drains each wave's DMA -> K(t+1),V(t+1) resident
  }
#undef ASTAGE

  // ---- epilogue: reduce lsum; write ctx (unsplit) or normalized partial (split) ----
#pragma unroll
  for (int qf = 0; qf < 2; ++qf) {
    float ls = lsum[qf];
    ls += __shfl_xor(ls, 16);
    ls += __shfl_xor(ls, 32);           // all lanes: row-total for row lr of this qf
    float rl = 1.0f / ls;
    float r0 = __shfl(rl, 4 * lg + 0, 16);
    float r1 = __shfl(rl, 4 * lg + 1, 16);
    float r2 = __shfl(rl, 4 * lg + 2, 16);
    float r3 = __shfl(rl, 4 * lg + 3, 16);
    if (!split) {
      size_t obase = (size_t)(bS + qw + qf * 16 + 4 * lg) * HID + h128;
#pragma unroll
      for (int nj = 0; nj < 8; ++nj) {
        ctx[obase + 0 * HID + nj * 16 + lr] = f2bf(oacc[qf][nj][0] * r0);
        ctx[obase + 1 * HID + nj * 16 + lr] = f2bf(oacc[qf][nj][1] * r1);
        ctx[obase + 2 * HID + nj * 16 + lr] = f2bf(oacc[qf][nj][2] * r2);
        ctx[obase + 3 * HID + nj * 16 + lr] = f2bf(oacc[qf][nj][3] * r3);
      }
    } else {
      int t256 = (qt - 8) * 32 + bh;    // 0..255
      int rowq = w * 32 + qf * 16 + 4 * lg;  // row within q-tile
      size_t pbase = ((size_t)(half * 256 + t256) * 128 + rowq) * 128;
#pragma unroll
      for (int nj = 0; nj < 8; ++nj) {
        pO[pbase + 0 * 128 + nj * 16 + lr] = f2bf(oacc[qf][nj][0] * r0);
        pO[pbase + 1 * 128 + nj * 16 + lr] = f2bf(oacc[qf][nj][1] * r1);
        pO[pbase + 2 * 128 + nj * 16 + lr] = f2bf(oacc[qf][nj][2] * r2);
        pO[pbase + 3 * 128 + nj * 16 + lr] = f2bf(oacc[qf][nj][3] * r3);
      }
      if (lg == 0)
        pls[(half * 256 + t256) * 128 + w * 32 + qf * 16 + lr] = ls;
    }
  }
}

// ---------------- combine: ctx = (l1*O1 + l2*O2) / (l1+l2) for split q-tiles ----------------
__global__ __launch_bounds__(256) void combine(const unsigned short* __restrict__ pO,
                                               const float* __restrict__ pls,
                                               unsigned short* __restrict__ ctx) {
  int vid = blockIdx.x * 256 + threadIdx.x;   // 524288 threads, 8 elems each
  int t = vid >> 11;          // q-tile 0..255: qt8 = t>>5, bh = t&31
  int rr = (vid >> 4) & 127;  // row within q-tile
  int d8 = vid & 15;
  int qt8 = t >> 5, bh = t & 31, b = bh >> 4, h = bh & 15;
  float l1 = pls[t * 128 + rr];
  float l2 = pls[(256 + t) * 128 + rr];
  float inv = 1.0f / (l1 + l2);
  float w1 = l1 * inv, w2 = l2 * inv;
  u16x8 a = *(const u16x8*)&pO[((size_t)t * 128 + rr) * 128 + d8 * 8];
  u16x8 c = *(const u16x8*)&pO[((size_t)(256 + t) * 128 + rr) * 128 + d8 * 8];
  u16x8 o;
#pragma unroll
  for (int j = 0; j < 8; ++j) o[j] = f2bf(bf2f(a[j]) * w1 + bf2f(c[j]) * w2);
  size_t obase = (size_t)(b * S_LEN + (qt8 + 8) * 128 + rr) * HID + h * HD + d8 * 8;
  *(u16x8*)&ctx[obase] = o;
}

// ---------------- launch ----------------
extern "C" void kernel_launch(void* const* d_in, const int* in_sizes, int n_in,
                              void* d_out, int out_size, void* d_ws, size_t ws_size,
                              hipStream_t stream) {
  const float* hs = (const float*)d_in[0];
  const float* Wq = (const float*)d_in[1];
  const float* Wk = (const float*)d_in[2];
  const float* Wv = (const float*)d_in[3];
  const float* Wo = (const float*)d_in[4];

  char* ws = (char*)d_ws;
  unsigned short* hsb  = (unsigned short*)(ws);                    // 16 MB (reused as ctx)
  unsigned short* wall = (unsigned short*)(ws + 16777216);         // Wq|Wk|Wv|Wo bf16, 32 MB
  unsigned short* qkb  = (unsigned short*)(ws + 50331648);         // fused Q|K [4096][4096], 32 MB
  unsigned short* vtb  = (unsigned short*)(ws + 83886080);         // V^T [2048][4096], 16 MB
  float* ctab = (float*)(ws + 100663296);                          // [2048][64]
  float* stab = (float*)(ws + 101187584);
  unsigned short* ctxb = hsb;  // overlay: hsb fully consumed before attn writes
  // attn partials overlay dead weight regions (free during attn):
  unsigned short* pO = wall;                                       // 16 MB (dead Wq|Wk)
  float* pls = (float*)(ws + 16777216 + 16777216);                 // 256 KB (dead Wv)

  cvt_all<<<25088, 256, 0, stream>>>(hs, Wq, Wk, Wv, Wo, hsb, wall, ctab, stab);

  // fused Q|K projection: C[4096][4096] via 256^2 8-phase kernel (256 blocks)
  gemm256<unsigned short><<<256, 512, 0, stream>>>(hsb, wall, qkb, BS_TOT, 2 * HID, HID);
  // V^T directly: C[o][bs] = sum_h Wv[o][h] * hs[bs][h]  (128^2 kernel, 512 blocks)
  gemm128<unsigned short><<<512, 256, 0, stream>>>(wall + 2 * (size_t)HID * HID, hsb, vtb, HID, BS_TOT, HID);

  rope_apply_k<<<4096, 256, 0, stream>>>(qkb, ctab, stab);

  attn_fwd<<<768, 256, 0, stream>>>(qkb, vtb, ctxb, ctab, stab, pO, pls);
  combine<<<2048, 256, 0, stream>>>(pO, pls, ctxb);

  gemm128<float><<<512, 256, 0, stream>>>(ctxb, wall + 3 * (size_t)HID * HID, (float*)d_out, BS_TOT, HID, HID);

  (void)in_sizes; (void)n_in; (void)out_size; (void)ws_size;
}

// Round 18
// 263.621 us; speedup vs baseline: 1.1247x; 1.1247x over previous
//
#include <hip/hip_runtime.h>

#define S_LEN 2048
#define HID   2048
#define NHEAD 16
#define HD    128
#define BSZ   2
#define BS_TOT (BSZ * S_LEN)   // 4096
#define QKS   4096             // row stride of fused QK buffer

typedef __bf16 bf16x8 __attribute__((ext_vector_type(8)));
typedef unsigned short u16x8 __attribute__((ext_vector_type(8)));
typedef unsigned short u16x4 __attribute__((ext_vector_type(4)));
typedef float f32x4 __attribute__((ext_vector_type(4)));

static __device__ __forceinline__ bf16x8 as_bf(u16x8 v) { return __builtin_bit_cast(bf16x8, v); }

static __device__ __forceinline__ unsigned short f2bf(float f) {
  __bf16 h = (__bf16)f;
  return __builtin_bit_cast(unsigned short, h);
}
static __device__ __forceinline__ float bf2f(unsigned short b) {
  unsigned int u = ((unsigned int)b) << 16;
  return __builtin_bit_cast(float, u);
}

// async global->LDS 16B per lane; LDS dst = wave-uniform base + lane*16
static __device__ __forceinline__ void gload_lds16(const unsigned short* g, unsigned short* l) {
  __builtin_amdgcn_global_load_lds((const __attribute__((address_space(1))) unsigned int*)g,
                                   (__attribute__((address_space(3))) unsigned int*)l, 16, 0, 0);
}

// ---------------- fused converts + rope table (one launch) ----------------
__global__ __launch_bounds__(256) void cvt_all(const float* __restrict__ hs,
                                               const float* __restrict__ Wq,
                                               const float* __restrict__ Wk,
                                               const float* __restrict__ Wv,
                                               const float* __restrict__ Wo,
                                               unsigned short* __restrict__ hsb,
                                               unsigned short* __restrict__ wall,
                                               float* __restrict__ ct, float* __restrict__ st) {
  int b = (int)blockIdx.x, tid = (int)threadIdx.x;
  if (b < 8192) {                       // hidden states: 8.39M floats
    int i = b * 256 + tid;
    float4 v = ((const float4*)hs)[i];
    ushort4 o; o.x = f2bf(v.x); o.y = f2bf(v.y); o.z = f2bf(v.z); o.w = f2bf(v.w);
    ((ushort4*)hsb)[i] = o;
  } else if (b < 24576) {               // 4 weights, 4096 blocks each
    int t = b - 8192;
    int wsel = t >> 12;
    const float* in = (wsel == 0) ? Wq : (wsel == 1) ? Wk : (wsel == 2) ? Wv : Wo;
    int i = (t & 4095) * 256 + tid;
    float4 v = ((const float4*)in)[i];
    ushort4 o; o.x = f2bf(v.x); o.y = f2bf(v.y); o.z = f2bf(v.z); o.w = f2bf(v.w);
    ((ushort4*)(wall + (size_t)wsel * HID * HID))[i] = o;
  } else {                              // rope table: 512 blocks -> [2048][64]
    int id = (b - 24576) * 256 + tid;
    int tt = id >> 6, d = id & 63;
    float inv = powf(10000.0f, -(float)d * (1.0f / 64.0f));
    float f = (float)tt * inv;
    float sv, cv;
    sincosf(f, &sv, &cv);
    ct[id] = cv; st[id] = sv;
  }
}

// ---------------- RoPE apply in-place on K half of fused QK buffer ----------------
__global__ __launch_bounds__(256) void rope_apply_k(unsigned short* __restrict__ qk,
                                                    const float* __restrict__ ct,
                                                    const float* __restrict__ st) {
  int id = blockIdx.x * 256 + threadIdx.x;   // BS_TOT*NHEAD*16 threads; each does 4 d's
  int d4 = (id & 15) * 4;
  int h = (id >> 4) & (NHEAD - 1);
  int m = id >> 8;
  int s = m & (S_LEN - 1);
  float4 c  = *(const float4*)(ct + s * 64 + d4);
  float4 sn = *(const float4*)(st + s * 64 + d4);
  size_t base = (size_t)m * QKS + 2048 + h * HD + d4;   // K half
  u16x4 k1 = *(u16x4*)(qk + base), k2 = *(u16x4*)(qk + base + 64);
  u16x4 p1, p2;
  float cc[4] = {c.x, c.y, c.z, c.w}, ss[4] = {sn.x, sn.y, sn.z, sn.w};
#pragma unroll
  for (int j = 0; j < 4; ++j) {
    float ak = bf2f(k1[j]), bk = bf2f(k2[j]);
    p1[j] = f2bf(ak * cc[j] - bk * ss[j]);
    p2[j] = f2bf(bk * cc[j] + ak * ss[j]);
  }
  *(u16x4*)(qk + base) = p1;
  *(u16x4*)(qk + base + 64) = p2;
}

// ---------------- GEMM 256x256, BK=64, 8 waves (2Mx4N), 8-phase schedule ----------------
template <typename OutT>
__global__ __launch_bounds__(512, 1) void gemm256(const unsigned short* __restrict__ A,
                                                  const unsigned short* __restrict__ Bw,
                                                  OutT* __restrict__ C, int M, int N, int K) {
  __shared__ __align__(16) unsigned short As[2][256 * 64];
  __shared__ __align__(16) unsigned short Bs[2][256 * 64];
  int x = (int)blockIdx.x;
  int chunk = (int)gridDim.x >> 3;
  int x2 = (x & 7) * chunk + (x >> 3);   // XCD-contiguous chunks (grid % 8 == 0)
  const int nbn = N >> 8;
  int bm = x2 / nbn, bn = x2 % nbn;
  int tid = (int)threadIdx.x;
  int l = tid & 63, lr = l & 15, lg = l >> 4;
  int w = tid >> 6;                      // 0..7
  int wm = w >> 2, wn = w & 3;

  // staging sources (sigma = row&7 = l>>3 folded into per-lane global col)
  int arow0 = wm * 128 + 8 * (w & 3) + (l >> 3);   // + 32c per A-chunk
  int brow0 = 8 * w + (l >> 3);                    // + 64c per B-chunk
  int sslot = ((l & 7) ^ (l >> 3)) * 8;
  const unsigned short* gAb = A + (size_t)(bm * 256 + arow0) * K + sslot;
  const unsigned short* gBb = Bw + (size_t)(bn * 256 + brow0) * K + sslot;

  // frag read bases (row stride 64 elems; 16 rows = 1024 elems)
  int arw = (wm * 128 + lr) * 64;
  int brw = (wn * 64 + lr) * 64;
  int acol0 = ((0 + lg) ^ (lr & 7)) * 8;   // ks=0 slots 0..3
  int acol1 = ((4 + lg) ^ (lr & 7)) * 8;   // ks=1 slots 4..7

  f32x4 zero = {0.f, 0.f, 0.f, 0.f};
  f32x4 acc[8][4];
#pragma unroll
  for (int mi = 0; mi < 8; ++mi)
#pragma unroll
    for (int ni = 0; ni < 4; ++ni) acc[mi][ni] = zero;

  int nk = K >> 6;        // K-tiles of 64 (K=2048 -> 32, pow2)
  int nk2 = nk >> 1;

#define ISSUE_A(buf, tile, c)                                                  \
  gload_lds16(gAb + (size_t)(32 * (c)) * K + (tile) * 64,                      \
              &As[buf][8192 * wm + 2048 * (c) + 512 * (w & 3)])
#define ISSUE_B(buf, tile, c)                                                  \
  gload_lds16(gBb + (size_t)(64 * (c)) * K + (tile) * 64,                      \
              &Bs[buf][4096 * (c) + 512 * w])
#define HT(buf, tile, c)                                                       \
  do { ISSUE_B(buf, tile, c); ISSUE_A(buf, tile, c); } while (0)
#define VM6 asm volatile("s_waitcnt vmcnt(6)" ::: "memory")

#define LOADB(d)                                                               \
  do {                                                                         \
    _Pragma("unroll") for (int ni = 0; ni < 4; ++ni) {                         \
      bfr[ni][0] = *(const u16x8*)&Bs[d][brw + ni * 1024 + acol0];             \
      bfr[ni][1] = *(const u16x8*)&Bs[d][brw + ni * 1024 + acol1];             \
    }                                                                          \
  } while (0)

#define PHASE(d, q, LASTW, ...)                                                \
  do {                                                                         \
    u16x8 paf[2][2];                                                           \
    _Pragma("unroll") for (int m2 = 0; m2 < 2; ++m2) {                         \
      paf[m2][0] = *(const u16x8*)&As[d][arw + ((q) * 2 + m2) * 1024 + acol0]; \
      paf[m2][1] = *(const u16x8*)&As[d][arw + ((q) * 2 + m2) * 1024 + acol1]; \
    }                                                                          \
    __VA_ARGS__;                                                               \
    __builtin_amdgcn_sched_barrier(0);                                         \
    __builtin_amdgcn_s_barrier();                                              \
    __builtin_amdgcn_s_setprio(1);                                             \
    _Pragma("unroll") for (int m2 = 0; m2 < 2; ++m2)                           \
      _Pragma("unroll") for (int ni = 0; ni < 4; ++ni) {                       \
        acc[(q) * 2 + m2][ni] = __builtin_amdgcn_mfma_f32_16x16x32_bf16(       \
            as_bf(paf[m2][0]), as_bf(bfr[ni][0]), acc[(q) * 2 + m2][ni], 0, 0, 0); \
        acc[(q) * 2 + m2][ni] = __builtin_amdgcn_mfma_f32_16x16x32_bf16(       \
            as_bf(paf[m2][1]), as_bf(bfr[ni][1]), acc[(q) * 2 + m2][ni], 0, 0, 0); \
      }                                                                        \
    __builtin_amdgcn_s_setprio(0);                                             \
    LASTW;                                                                     \
    __builtin_amdgcn_s_barrier();                                              \
  } while (0)

  // prologue: tile0 4 half-tiles + tile1 3 half-tiles (14 loads), land tile0, sync
  HT(0, 0, 0); HT(0, 0, 1); HT(0, 0, 2); HT(0, 0, 3);
  HT(1, 1, 0); HT(1, 1, 1); HT(1, 1, 2);
  VM6;
  __builtin_amdgcn_s_barrier();

  for (int t = 0; t < nk2; ++t) {
    int Todd = 2 * t + 1;                 // always < nk
    int T2 = (2 * t + 2) & (nk - 1);      // wrap-around dummies at tail
    int T3 = (2 * t + 3) & (nk - 1);
    u16x8 bfr[4][2];
    LOADB(0);
    PHASE(0, 0, (void)0, HT(1, Todd, 3));
    PHASE(0, 1, (void)0, HT(0, T2, 0));
    PHASE(0, 2, (void)0, HT(0, T2, 1));
    PHASE(0, 3, VM6,     HT(0, T2, 2));
    LOADB(1);
    PHASE(1, 0, (void)0, HT(0, T2, 3));
    PHASE(1, 1, (void)0, HT(1, T3, 0));
    PHASE(1, 2, (void)0, HT(1, T3, 1));
    PHASE(1, 3, VM6,     HT(1, T3, 2));
  }
#undef PHASE
#undef LOADB
#undef VM6
#undef HT
#undef ISSUE_A
#undef ISSUE_B

#pragma unroll
  for (int mi = 0; mi < 8; ++mi) {
#pragma unroll
    for (int ni = 0; ni < 4; ++ni) {
      int col = bn * 256 + wn * 64 + ni * 16 + lr;
#pragma unroll
      for (int j = 0; j < 4; ++j) {
        int rowm = bm * 256 + wm * 128 + mi * 16 + 4 * lg + j;
        float v = acc[mi][ni][j];
        if constexpr (sizeof(OutT) == 2) C[(size_t)rowm * N + col] = f2bf(v);
        else                             C[(size_t)rowm * N + col] = v;
      }
    }
  }
  (void)M;
}

// ---------------- GEMM 128x128, BK=32, 4 waves; 4-buffer counted-vmcnt ----------------
template <typename OutT>
__global__ __launch_bounds__(256) void gemm128(const unsigned short* __restrict__ A,
                                               const unsigned short* __restrict__ Bw,
                                               OutT* __restrict__ C, int M, int N, int K) {
  __shared__ __align__(16) unsigned short As[4][128 * 32];
  __shared__ __align__(16) unsigned short Bs[4][128 * 32];
  int x = (int)blockIdx.x;
  int chunk = (int)gridDim.x >> 3;
  int x2 = (x & 7) * chunk + (x >> 3);
  const int nbn = N >> 7;
  int bm = x2 / nbn, bn = x2 % nbn;
  int tid = (int)threadIdx.x;
  int l = tid & 63, lr = l & 15, lg = l >> 4;
  int w = tid >> 6, wm = w >> 1, wn = w & 1;

  int w32 = 32 * w;
  int srow = w32 + (l >> 2);
  int ssw = ((l >> 2) ^ (l >> 4)) & 3;
  const unsigned short* gA = A + (size_t)(bm * 128 + srow) * K + (((l & 3) ^ ssw) << 3);
  const unsigned short* gB = Bw + (size_t)(bn * 128 + srow) * K + (((l & 3) ^ ssw) << 3);

  int rsw = (lr ^ (lr >> 2)) & 3;
  int aoff[4], boff[4];
#pragma unroll
  for (int i = 0; i < 4; ++i) {
    aoff[i] = (wm * 64 + i * 16 + lr) * 32 + ((lg ^ rsw) << 3);
    boff[i] = (wn * 64 + i * 16 + lr) * 32 + ((lg ^ rsw) << 3);
  }

  f32x4 zero = {0.f, 0.f, 0.f, 0.f};
  f32x4 acc[4][4];
#pragma unroll
  for (int mi = 0; mi < 4; ++mi)
#pragma unroll
    for (int ni = 0; ni < 4; ++ni) acc[mi][ni] = zero;

  int nk = K >> 5;

#define STAGE(buf, kt)                                                        \
  do {                                                                        \
    const unsigned short* pa_ = gA + (size_t)(kt) * 32;                       \
    const unsigned short* pb_ = gB + (size_t)(kt) * 32;                       \
    gload_lds16(pa_, &As[buf][w32 * 32]);                                     \
    gload_lds16(pa_ + (size_t)16 * K, &As[buf][(w32 + 16) * 32]);             \
    gload_lds16(pb_, &Bs[buf][w32 * 32]);                                     \
    gload_lds16(pb_ + (size_t)16 * K, &Bs[buf][(w32 + 16) * 32]);             \
  } while (0)

#define COMPUTE(buf)                                                          \
  do {                                                                        \
    u16x8 af[4], bfr[4];                                                      \
    _Pragma("unroll") for (int i = 0; i < 4; ++i) {                           \
      af[i] = *(const u16x8*)&As[buf][aoff[i]];                               \
      bfr[i] = *(const u16x8*)&Bs[buf][boff[i]];                              \
    }                                                                         \
    _Pragma("unroll") for (int mi = 0; mi < 4; ++mi)                          \
        _Pragma("unroll") for (int ni = 0; ni < 4; ++ni)                      \
            acc[mi][ni] = __builtin_amdgcn_mfma_f32_16x16x32_bf16(            \
                as_bf(af[mi]), as_bf(bfr[ni]), acc[mi][ni], 0, 0, 0);         \
  } while (0)

  STAGE(0, 0);
  STAGE(1, 1);
  STAGE(2, 2);
  asm volatile("s_waitcnt vmcnt(8)" ::: "memory");
  __builtin_amdgcn_s_barrier();
#pragma unroll 4
  for (int kt = 0; kt < nk; ++kt) {
    COMPUTE(kt & 3);
    asm volatile("s_waitcnt vmcnt(4) lgkmcnt(0)" ::: "memory");
    __builtin_amdgcn_s_barrier();
    STAGE((kt + 3) & 3, (kt + 3) & (nk - 1));
  }
#undef STAGE
#undef COMPUTE

#pragma unroll
  for (int mi = 0; mi < 4; ++mi) {
#pragma unroll
    for (int ni = 0; ni < 4; ++ni) {
      int col = bn * 128 + wn * 64 + ni * 16 + lr;
#pragma unroll
      for (int j = 0; j < 4; ++j) {
        int rowm = bm * 128 + wm * 64 + mi * 16 + 4 * lg + j;
        float v = acc[mi][ni][j];
        if constexpr (sizeof(OutT) == 2) C[(size_t)rowm * N + col] = f2bf(v);
        else                             C[(size_t)rowm * N + col] = v;
      }
    }
  }
  (void)M;
}

// ---------------- Flash attention v7: fixed-max softmax, fused Q-rope, PV interleave ----------------
__global__ __launch_bounds__(256, 2) void attn_fwd(const unsigned short* __restrict__ qk,
                                                   const unsigned short* __restrict__ vt,
                                                   unsigned short* __restrict__ ctx,
                                                   const float* __restrict__ ct,
                                                   const float* __restrict__ st) {
  __shared__ __align__(16) unsigned short Ks[2][64 * 128];   // [kv][d], sigma(r)=r&15 on 16B slots
  __shared__ __align__(16) unsigned short Vs[2][128 * 64];   // [d][kv], sigma(d)=d&7
  __shared__ __align__(16) unsigned short Ps[4 * 32 * 64];   // per-wave P, 8B-slot swizzled

  int x = (int)blockIdx.x;            // 512 blocks; pair (heavy 15-g, light g) per CU
  int bh, qt;
  if (x < 256) { bh = x & 31;         qt = 15 - (x >> 5); }
  else         { bh = (x - 256) & 31; qt = (x - 256) >> 5; }
  int b = bh >> 4, h = bh & 15;
  int q0 = qt * 128;
  int nt = 2 * qt + 2;                // even

  int tid = (int)threadIdx.x;
  int w = tid >> 6, l = tid & 63, lr = l & 15, lg = l >> 4;
  const float CEXP = 0.12751744f;     // (1/sqrt(128)) * log2(e)
  const float MB   = -23.0831391f;    // -16 * log2(e): fixed-max shift
  const int bS = b * S_LEN, h128 = h * HD;
  const int qw = q0 + w * 32;
  const unsigned short* qg = qk;
  const unsigned short* kg = qk + 2048;

  // ---- Q fragments + in-register RoPE ----
  u16x8 qfr[2][4];
#pragma unroll
  for (int qf = 0; qf < 2; ++qf) {
    const unsigned short* qb = qg + (size_t)(bS + qw + qf * 16 + lr) * QKS + h128;
#pragma unroll
    for (int kk = 0; kk < 4; ++kk) qfr[qf][kk] = *(const u16x8*)(qb + kk * 32 + lg * 8);
    int spos = qw + qf * 16 + lr;     // seq position (< 2048)
#pragma unroll
    for (int kk = 0; kk < 2; ++kk) {
      int d0 = kk * 32 + lg * 8;
      float4 c0 = *(const float4*)(ct + spos * 64 + d0);
      float4 c1 = *(const float4*)(ct + spos * 64 + d0 + 4);
      float4 s0 = *(const float4*)(st + spos * 64 + d0);
      float4 s1 = *(const float4*)(st + spos * 64 + d0 + 4);
      float cc[8] = {c0.x, c0.y, c0.z, c0.w, c1.x, c1.y, c1.z, c1.w};
      float sv[8] = {s0.x, s0.y, s0.z, s0.w, s1.x, s1.y, s1.z, s1.w};
      u16x8 lo = qfr[qf][kk], hi = qfr[qf][kk + 2];
#pragma unroll
      for (int j = 0; j < 8; ++j) {
        float a = bf2f(lo[j]), b2 = bf2f(hi[j]);
        lo[j] = f2bf(a * cc[j] - b2 * sv[j]);
        hi[j] = f2bf(b2 * cc[j] + a * sv[j]);
      }
      qfr[qf][kk] = lo; qfr[qf][kk + 2] = hi;
    }
  }

  // staging sources (sigma folded into per-lane global col, rule 21)
  const unsigned short* kbg[4];
  const unsigned short* vbg[4];
#pragma unroll
  for (int i = 0; i < 4; ++i) {
    int rr = 16 * w + 4 * i + (l >> 4);           // local kv row 0..63
    int colK = ((l & 15) ^ (rr & 15)) * 8;
    kbg[i] = kg + (size_t)(bS + rr) * QKS + h128 + colK;
    int vd = 32 * w + 8 * i + (l >> 3);           // local d row 0..127
    int colV = ((l & 7) ^ (vd & 7)) * 8;
    vbg[i] = vt + (size_t)(h128 + vd) * BS_TOT + bS + colV;
  }

#define ASTAGE(buf, t)                                                        \
  do {                                                                        \
    size_t koff_ = (size_t)(t) * 64 * QKS;                                    \
    int voff_ = (t) * 64;                                                     \
    _Pragma("unroll") for (int i_ = 0; i_ < 4; ++i_) {                        \
      gload_lds16(kbg[i_] + koff_, &Ks[buf][(16 * w + 4 * i_) * 128]);        \
      gload_lds16(vbg[i_] + voff_, &Vs[buf][(32 * w + 8 * i_) * 64]);         \
    }                                                                         \
  } while (0)

  f32x4 zero = {0.f, 0.f, 0.f, 0.f};
  f32x4 oacc[2][8];
#pragma unroll
  for (int qf = 0; qf < 2; ++qf)
#pragma unroll
    for (int nj = 0; nj < 8; ++nj) oacc[qf][nj] = zero;
  float lsum[2] = {0.f, 0.f};   // per-lane partials; reduced in epilogue

  int cur = 0;
  ASTAGE(0, 0);
  __syncthreads();

  for (int t = 0; t < nt; ++t) {
    int k0 = t * 64;
    if (t + 1 < nt) ASTAGE(cur ^ 1, t + 1);

    if (k0 <= qw + 31) {
      const unsigned short* KsB = &Ks[cur][0];
      const unsigned short* VsB = &Vs[cur][0];

      // ---- S^T = K Q^T for both qf ----
      f32x4 sac[2][4];
#pragma unroll
      for (int qf = 0; qf < 2; ++qf)
#pragma unroll
        for (int ni = 0; ni < 4; ++ni) sac[qf][ni] = zero;
      __builtin_amdgcn_s_setprio(1);
#pragma unroll
      for (int kk = 0; kk < 4; ++kk) {
#pragma unroll
        for (int ni = 0; ni < 4; ++ni) {
          u16x8 kf = *(const u16x8*)&KsB[(ni * 16 + lr) * 128 + (((kk * 4 + lg) ^ lr) * 8)];
          sac[0][ni] = __builtin_amdgcn_mfma_f32_16x16x32_bf16(as_bf(kf), as_bf(qfr[0][kk]), sac[0][ni], 0, 0, 0);
          sac[1][ni] = __builtin_amdgcn_mfma_f32_16x16x32_bf16(as_bf(kf), as_bf(qfr[1][kk]), sac[1][ni], 0, 0, 0);
        }
      }
      __builtin_amdgcn_s_setprio(0);

      // ---- hoist V fragments to registers (LDS reads shared by both qf PVs) ----
      u16x8 vfr[2][8];
#pragma unroll
      for (int kk2 = 0; kk2 < 2; ++kk2)
#pragma unroll
        for (int nj = 0; nj < 8; ++nj)
          vfr[kk2][nj] = *(const u16x8*)&VsB[(nj * 16 + lr) * 64 + (((kk2 * 4 + lg) ^ (lr & 7)) * 8)];

      bool needmask = (k0 + 63 > qw);
      unsigned short* pw = &Ps[w * 2048];

      // ---- per-qf: softmax -> P-write -> PV (PV_qf0 MFMAs overlap softmax_qf1 VALU) ----
#pragma unroll
      for (int qf = 0; qf < 2; ++qf) {
        float s[4][4];
#pragma unroll
        for (int ni = 0; ni < 4; ++ni)
#pragma unroll
          for (int j = 0; j < 4; ++j) s[ni][j] = sac[qf][ni][j];
        if (needmask) {
          int qgl = qw + qf * 16 + lr;
#pragma unroll
          for (int ni = 0; ni < 4; ++ni)
#pragma unroll
            for (int j = 0; j < 4; ++j)
              if (k0 + ni * 16 + 4 * lg + j > qgl) s[ni][j] = -1e30f;
        }
        // fixed-max softmax: p = exp2(s*CEXP + MB); masked -> exp2(-huge) = 0
        float rs = 0.f;
#pragma unroll
        for (int ni = 0; ni < 4; ++ni)
#pragma unroll
          for (int j = 0; j < 4; ++j) {
            float p = exp2f(fmaf(s[ni][j], CEXP, MB));
            s[ni][j] = p; rs += p;
          }
        lsum[qf] += rs;
#pragma unroll
        for (int ni = 0; ni < 4; ++ni) {
          u16x4 pv = {f2bf(s[ni][0]), f2bf(s[ni][1]), f2bf(s[ni][2]), f2bf(s[ni][3])};
          *(u16x4*)&pw[(qf * 16 + lr) * 64 + (((2 * ni + (lg >> 1)) ^ (lr & 7)) * 8) + (lg & 1) * 4] = pv;
        }
        // PV for this qf immediately (reads only this qf's P region)
        __builtin_amdgcn_s_setprio(1);
#pragma unroll
        for (int kk2 = 0; kk2 < 2; ++kk2) {
          u16x8 pa = *(const u16x8*)&pw[(qf * 16 + lr) * 64 + (((kk2 * 4 + lg) ^ (lr & 7)) * 8)];
#pragma unroll
          for (int nj = 0; nj < 8; ++nj)
            oacc[qf][nj] = __builtin_amdgcn_mfma_f32_16x16x32_bf16(as_bf(pa), as_bf(vfr[kk2][nj]), oacc[qf][nj], 0, 0, 0);
        }
        __builtin_amdgcn_s_setprio(0);
      }
    }

    __syncthreads();
    cur ^= 1;
  }
#undef ASTAGE

  // ---- epilogue: reduce lsum, ctx[q][h*128+d] = O / lsum ----
#pragma unroll
  for (int qf = 0; qf < 2; ++qf) {
    float ls = lsum[qf];
    ls += __shfl_xor(ls, 16);
    ls += __shfl_xor(ls, 32);
    float rl = 1.0f / ls;
    float r0 = __shfl(rl, 4 * lg + 0, 16);
    float r1 = __shfl(rl, 4 * lg + 1, 16);
    float r2 = __shfl(rl, 4 * lg + 2, 16);
    float r3 = __shfl(rl, 4 * lg + 3, 16);
    size_t obase = (size_t)(bS + qw + qf * 16 + 4 * lg) * HID + h128;
#pragma unroll
    for (int nj = 0; nj < 8; ++nj) {
      ctx[obase + 0 * HID + nj * 16 + lr] = f2bf(oacc[qf][nj][0] * r0);
      ctx[obase + 1 * HID + nj * 16 + lr] = f2bf(oacc[qf][nj][1] * r1);
      ctx[obase + 2 * HID + nj * 16 + lr] = f2bf(oacc[qf][nj][2] * r2);
      ctx[obase + 3 * HID + nj * 16 + lr] = f2bf(oacc[qf][nj][3] * r3);
    }
  }
}

// ---------------- launch ----------------
extern "C" void kernel_launch(void* const* d_in, const int* in_sizes, int n_in,
                              void* d_out, int out_size, void* d_ws, size_t ws_size,
                              hipStream_t stream) {
  const float* hs = (const float*)d_in[0];
  const float* Wq = (const float*)d_in[1];
  const float* Wk = (const float*)d_in[2];
  const float* Wv = (const float*)d_in[3];
  const float* Wo = (const float*)d_in[4];

  char* ws = (char*)d_ws;
  unsigned short* hsb  = (unsigned short*)(ws);                    // 16 MB (reused as ctx)
  unsigned short* wall = (unsigned short*)(ws + 16777216);         // Wq|Wk|Wv|Wo bf16, 32 MB
  unsigned short* qkb  = (unsigned short*)(ws + 50331648);         // fused Q|K [4096][4096], 32 MB
  unsigned short* vtb  = (unsigned short*)(ws + 83886080);         // V^T [2048][4096], 16 MB
  float* ctab = (float*)(ws + 100663296);                          // [2048][64]
  float* stab = (float*)(ws + 101187584);
  unsigned short* ctxb = hsb;  // overlay: hsb fully consumed before attn writes

  cvt_all<<<25088, 256, 0, stream>>>(hs, Wq, Wk, Wv, Wo, hsb, wall, ctab, stab);

  // fused Q|K projection: C[4096][4096] via 256^2 8-phase kernel (256 blocks)
  gemm256<unsigned short><<<256, 512, 0, stream>>>(hsb, wall, qkb, BS_TOT, 2 * HID, HID);
  // V^T directly: C[o][bs] = sum_h Wv[o][h] * hs[bs][h]  (128^2 kernel, 512 blocks)
  gemm128<unsigned short><<<512, 256, 0, stream>>>(wall + 2 * (size_t)HID * HID, hsb, vtb, HID, BS_TOT, HID);

  rope_apply_k<<<4096, 256, 0, stream>>>(qkb, ctab, stab);

  attn_fwd<<<512, 256, 0, stream>>>(qkb, vtb, ctxb, ctab, stab);

  gemm128<float><<<512, 256, 0, stream>>>(ctxb, wall + 3 * (size_t)HID * HID, (float*)d_out, BS_TOT, HID, HID);

  (void)in_sizes; (void)n_in; (void)out_size; (void)ws_size;
}